// Round 8
// baseline (270.855 us; speedup 1.0000x reference)
//
#include <hip/hip_runtime.h>
#include <hip/hip_bf16.h>

// Problem constants: b=4, n=8192, dim=256, heads=8, dhead=64, inner=512
#define SEQ    8192
#define EPS    1e-5f

typedef __attribute__((ext_vector_type(4))) float f32x4;
typedef __attribute__((ext_vector_type(8))) short bf16x8;          // 8 bf16 (MFMA A/B frag)
typedef __attribute__((ext_vector_type(8))) unsigned short u16x8;  // 16B bf16 load/store

__device__ __forceinline__ unsigned short f2bu(float f) {
  __hip_bfloat16 h = __float2bfloat16(f);
  return __builtin_bit_cast(unsigned short, h);
}
__device__ __forceinline__ float b2f(unsigned short u) {
  return __bfloat162float(__builtin_bit_cast(__hip_bfloat16, u));
}

// ---------------------------------------------------------------- prep: x f32->bf16, Wqkv f32->bf16 (+ wqT transpose)
__global__ __launch_bounds__(256) void prep_kernel(const float* __restrict__ x,
                                                   const float* __restrict__ W,
                                                   unsigned short* __restrict__ xb,
                                                   unsigned short* __restrict__ wb,
                                                   unsigned short* __restrict__ wqT) {
  const int bid = blockIdx.x;
  const int t = threadIdx.x;
  if (bid < 8192) {
    const int i = bid * 256 + t;                 // 2097152 float4 groups
    float4 v = reinterpret_cast<const float4*>(x)[i];
    ushort4 o;
    o.x = f2bu(v.x); o.y = f2bu(v.y); o.z = f2bu(v.z); o.w = f2bu(v.w);
    reinterpret_cast<ushort4*>(xb)[i] = o;
  } else {
    const int i = (bid - 8192) * 256 + t;        // 98304 float4 groups (1536*256/4)
    float4 v = reinterpret_cast<const float4*>(W)[i];
    ushort4 o;
    o.x = f2bu(v.x); o.y = f2bu(v.y); o.z = f2bu(v.z); o.w = f2bu(v.w);
    reinterpret_cast<ushort4*>(wb)[i] = o;
    const int e = i * 4;
    const int f = e >> 8;                        // row in [0,1536)
    if (f < 512) {                               // q rows -> scatter transpose
      const int c = e & 255;
      wqT[(size_t)(c + 0) * 512 + f] = o.x;
      wqT[(size_t)(c + 1) * 512 + f] = o.y;
      wqT[(size_t)(c + 2) * 512 + f] = o.z;
      wqT[(size_t)(c + 3) * 512 + f] = o.w;
    }
  }
}

// ---------------------------------------------------------------- fused kv-GEMM + instance-norm + partial k^T v
// 512 blocks (1D, XCD-pair swizzled), 512 threads (8 waves), 138240 B dynamic LDS.
// Block = (b, chunk of 512 rows, head h): loops 8 sub-chunks of 64 rows:
//   MFMA GEMM x[64x256] @ Wkv_h[128x256]^T -> kv tile in regs (f32)
//   -> row stats (shfl + LDS cross-wave) -> normalized f32 into lbuf
//   -> prefetch next x (issued after barriers; hides under dots phase)
//   -> dots outer-product accumulate (thread owns 4d x 2e).
// W/X LDS tiles XOR-chunk-swizzled BOTH-SIDES (pre-swizzled global src + swizzled ds_read).
#define KVD_LDS 138240
__global__ __launch_bounds__(512) void kvdots_kernel(const unsigned short* __restrict__ xb,
                                                     const unsigned short* __restrict__ wqkvb,
                                                     float* __restrict__ partial) {
  extern __shared__ char sm[];
  unsigned short* Ws = (unsigned short*)sm;               // [128][256]  65536 B
  unsigned short* Xs = (unsigned short*)(sm + 65536);     // [64][256]   32768 B
  float* lk  = (float*)(sm + 98304);                      // [64][68]    17408 B
  float* lv  = (float*)(sm + 98304 + 17408);              // [64][68]    17408 B
  float* ps  = (float*)(sm + 133120);                     // [8][64]      2048 B
  float* psq = (float*)(sm + 135168);                     // [8][64]      2048 B
  float* fin = (float*)(sm + 137216);                     // [2][64][2]   1024 B

  // XCD-pair swizzle: all 8 heads of one (b,chunk) land on the SAME XCD (x fetched once per L2)
  const int lin = blockIdx.x;            // 0..511
  const int j   = lin & 7;               // xcd
  const int m   = lin >> 3;              // 0..63
  const int h   = m & 7;
  const int pair = j * 8 + (m >> 3);     // 0..63
  const int b = pair >> 4, chunk = pair & 15;
  const int bh = b * 8 + h;

  const int t = threadIdx.x, l = t & 63, w = t >> 6;
  const int sub  = t >> 5;               // staging row-within-pass
  const int cb16 = (t & 31) << 4;        // staging byte col

  // ---- stage W (once) + x sub-chunk 0
#pragma unroll
  for (int p = 0; p < 8; ++p) {
    const int rw = p * 16 + sub;
    const int scb = cb16 ^ ((rw & 7) << 4);
    const int g = 512 + ((rw >> 6) << 9) + (h << 6) + (rw & 63);   // k rows then v rows of Wqkv
    __builtin_amdgcn_global_load_lds(
        (const __attribute__((address_space(1))) void*)(wqkvb + (size_t)g * 256 + (scb >> 1)),
        (__attribute__((address_space(3))) void*)(sm + p * 8192 + t * 16), 16, 0, 0);
  }
#pragma unroll
  for (int p = 0; p < 4; ++p) {
    const int rx = p * 16 + sub;
    const int scb = cb16 ^ ((rx & 7) << 4);
    const size_t g = (size_t)(b * SEQ + chunk * 512 + rx) * 256;
    __builtin_amdgcn_global_load_lds(
        (const __attribute__((address_space(1))) void*)(xb + g + (scb >> 1)),
        (__attribute__((address_space(3))) void*)(sm + 65536 + p * 8192 + t * 16), 16, 0, 0);
  }

  const int c    = (w << 4) + (l & 15);  // kv col 0..127 (0-63 = k, 64-127 = v)
  const int half = w >> 2;               // 0 = k waves, 1 = v waves
  const int d    = c & 63;
  const int g4   = l >> 4;               // 0..3
  const int dq   = t & 15;               // dots role: d-group (4 d's)
  const int eg   = t >> 4;               // dots role: e-group 0..31 (2 e's)

  float accd[4][2] = {};

  for (int s = 0; s < 8; ++s) {
    __syncthreads();                     // [A] Xs(s) staged (vmcnt drained); lbuf free
    // ---- GEMM: kv[r, c] for r in 0..63
    f32x4 acc[4] = {};
#pragma unroll
    for (int ks = 0; ks < 8; ++ks) {
      const int kb = (ks << 6) + (g4 << 4);
      const bf16x8 bfr = *reinterpret_cast<const bf16x8*>((char*)Ws + c * 512 + (kb ^ ((c & 7) << 4)));
#pragma unroll
      for (int mt = 0; mt < 4; ++mt) {
        const int r = (mt << 4) + (l & 15);
        const bf16x8 af = *reinterpret_cast<const bf16x8*>((char*)Xs + r * 512 + (kb ^ ((r & 7) << 4)));
        acc[mt] = __builtin_amdgcn_mfma_f32_16x16x32_bf16(af, bfr, acc[mt], 0, 0, 0);
      }
    }
    // ---- row stats: 16-col partial per wave via shfl over lane&15 groups
#pragma unroll
    for (int mt = 0; mt < 4; ++mt) {
#pragma unroll
      for (int i = 0; i < 4; ++i) {
        float a = acc[mt][i];
        float q = a * a;
#pragma unroll
        for (int mk = 1; mk <= 8; mk <<= 1) {
          a += __shfl_xor(a, mk, 64);
          q += __shfl_xor(q, mk, 64);
        }
        if ((l & 15) == 0) {
          const int r = (mt << 4) + (g4 << 2) + i;
          ps [(w << 6) + r] = a;
          psq[(w << 6) + r] = q;
        }
      }
    }
    __syncthreads();                     // [B] ps/psq ready; Xs fully consumed
    if (t < 128) {                       // finalize stats: one thread per (half, row)
      const int hf = t >> 6, r = t & 63;
      float a = 0.f, q = 0.f;
#pragma unroll
      for (int w2 = 0; w2 < 4; ++w2) {
        a += ps [(((hf << 2) + w2) << 6) + r];
        q += psq[(((hf << 2) + w2) << 6) + r];
      }
      const float mean = a * (1.0f / 64.0f);
      float var = q * (1.0f / 64.0f) - mean * mean;
      var = var < 0.f ? 0.f : var;
      fin[(hf << 7) + (r << 1)]     = mean;
      fin[(hf << 7) + (r << 1) + 1] = rsqrtf(var + EPS);
    }
    __syncthreads();                     // [C] fin ready
    {
      float* lb = half ? lv : lk;
#pragma unroll
      for (int mt = 0; mt < 4; ++mt) {
#pragma unroll
        for (int i = 0; i < 4; ++i) {
          const int r = (mt << 4) + (g4 << 2) + i;
          const float mean = fin[(half << 7) + (r << 1)];
          const float rs   = fin[(half << 7) + (r << 1) + 1];
          lb[r * 68 + d] = (acc[mt][i] - mean) * rs;
        }
      }
    }
    __syncthreads();                     // [D] lbuf ready
    if (s < 7) {                         // prefetch x(s+1): in flight through dots; drains at next [A]
#pragma unroll
      for (int p = 0; p < 4; ++p) {
        const int rx = p * 16 + sub;
        const int scb = cb16 ^ ((rx & 7) << 4);
        const size_t g = (size_t)(b * SEQ + chunk * 512 + (s + 1) * 64 + rx) * 256;
        __builtin_amdgcn_global_load_lds(
            (const __attribute__((address_space(1))) void*)(xb + g + (scb >> 1)),
            (__attribute__((address_space(3))) void*)(sm + 65536 + p * 8192 + t * 16), 16, 0, 0);
      }
    }
    // ---- dots accumulate: thread owns d = dq*4..+3, e = eg*2, eg*2+1
#pragma unroll 8
    for (int rr = 0; rr < 64; ++rr) {
      const f32x4 kf = *reinterpret_cast<const f32x4*>(lk + rr * 68 + (dq << 2));
      const float v0 = lv[rr * 68 + (eg << 1)];
      const float v1 = lv[rr * 68 + (eg << 1) + 1];
#pragma unroll
      for (int i = 0; i < 4; ++i) {
        accd[i][0] = fmaf(kf[i], v0, accd[i][0]);
        accd[i][1] = fmaf(kf[i], v1, accd[i][1]);
      }
    }
  }
  float* pp = partial + ((size_t)(chunk * 32 + bh) << 12) + (size_t)(dq << 2) * 64 + (eg << 1);
#pragma unroll
  for (int i = 0; i < 4; ++i) {
    pp[i * 64]     = accd[i][0];
    pp[i * 64 + 1] = accd[i][1];
  }
}

// ---------------------------------------------------------------- reduce 16 partials -> dots
__global__ __launch_bounds__(256) void reduce_kernel(const float* __restrict__ partial,
                                                     float* __restrict__ dots) {
  const int i = blockIdx.x * 256 + threadIdx.x;   // f32x4 index, 32768 total
  f32x4 s = {};
#pragma unroll
  for (int c = 0; c < 16; ++c)
    s += reinterpret_cast<const f32x4*>(partial)[(size_t)c * 32768 + i];
  reinterpret_cast<f32x4*>(dots)[i] = s;
}

// ---------------------------------------------------------------- M2[b*256+c, h*64+d] = (1/n) sum_e dots[b,h,d,e]*Wout[c,h*64+e]
__global__ __launch_bounds__(512) void m2_kernel(const float* __restrict__ dots,
                                                 const float* __restrict__ Wout,
                                                 unsigned short* __restrict__ M2) {
  const int b = blockIdx.x;
  const int c = blockIdx.y;
  const int t = threadIdx.x;
  __shared__ float wrow[512];
  wrow[t] = Wout[(size_t)c * 512 + t];
  __syncthreads();
  const int h = t >> 6, d = t & 63;
  const float* dp = dots + (size_t)(b * 8 + h) * 4096 + (size_t)d * 64;
  float s = 0.0f;
#pragma unroll 8
  for (int e = 0; e < 64; ++e) s += dp[e] * wrow[(h << 6) + e];
  M2[((size_t)b * 256 + c) * 512 + t] = f2bu(s * (1.0f / 8192.0f));
}

// ---------------------------------------------------------------- m97-style GEMM (tiny W3 = M2 @ WqT), bf16 out
template<int K, int LDA, int LDC>
__global__ __launch_bounds__(256) void gemm_kernel(const unsigned short* __restrict__ A,
                                                   const unsigned short* __restrict__ Bw,
                                                   void* __restrict__ Cout) {
  __shared__ char smem2[32768];
  unsigned short* As = (unsigned short*)smem2;
  unsigned short* Bs = (unsigned short*)(smem2 + 16384);
  const int row0 = blockIdx.y * 128;
  const int col0 = blockIdx.x * 128;
  const int tid  = threadIdx.x;
  const int lane = tid & 63;
  const int wave = tid >> 6;
  const int wr = (wave >> 1) << 6;
  const int wc = (wave & 1) << 6;
  const int srow = tid >> 3;
  const int scol = (tid & 7) << 3;
  f32x4 acc[4][4] = {};
  for (int k0 = 0; k0 < K; k0 += 64) {
#pragma unroll
    for (int it = 0; it < 4; ++it) {
      const unsigned short* ga = A + (size_t)(row0 + it * 32 + srow) * LDA + (k0 + scol);
      __builtin_amdgcn_global_load_lds(
          (const __attribute__((address_space(1))) void*)ga,
          (__attribute__((address_space(3))) void*)((char*)As + (it * 4096 + wave * 1024)), 16, 0, 0);
      const unsigned short* gb = Bw + (size_t)(col0 + it * 32 + srow) * K + (k0 + scol);
      __builtin_amdgcn_global_load_lds(
          (const __attribute__((address_space(1))) void*)gb,
          (__attribute__((address_space(3))) void*)((char*)Bs + (it * 4096 + wave * 1024)), 16, 0, 0);
    }
    __syncthreads();
#pragma unroll
    for (int ks = 0; ks < 2; ++ks) {
      bf16x8 af[4], bfr[4];
#pragma unroll
      for (int mt = 0; mt < 4; ++mt)
        af[mt] = *reinterpret_cast<const bf16x8*>(
            &As[(wr + mt * 16 + (lane & 15)) * 64 + ks * 32 + (lane >> 4) * 8]);
#pragma unroll
      for (int nt = 0; nt < 4; ++nt)
        bfr[nt] = *reinterpret_cast<const bf16x8*>(
            &Bs[(wc + nt * 16 + (lane & 15)) * 64 + ks * 32 + (lane >> 4) * 8]);
#pragma unroll
      for (int mt = 0; mt < 4; ++mt)
#pragma unroll
        for (int nt = 0; nt < 4; ++nt)
          acc[mt][nt] = __builtin_amdgcn_mfma_f32_16x16x32_bf16(af[mt], bfr[nt], acc[mt][nt], 0, 0, 0);
    }
    __syncthreads();
  }
#pragma unroll
  for (int mt = 0; mt < 4; ++mt)
#pragma unroll
    for (int nt = 0; nt < 4; ++nt) {
      const int col = col0 + wc + nt * 16 + (lane & 15);
#pragma unroll
      for (int i = 0; i < 4; ++i) {
        const int row = row0 + wr + mt * 16 + ((lane >> 4) << 2) + i;
        reinterpret_cast<unsigned short*>(Cout)[(size_t)row * LDC + col] = f2bu(acc[mt][nt][i]);
      }
    }
}

// ---------------------------------------------------------------- out = x @ W3^T + bout (f32)
// 64x128 tile, BK=64 2-barrier loop, 24 KB LDS, 256 thr -> 4 blocks/CU co-resident.
__global__ __launch_bounds__(256) void gemm_out(const unsigned short* __restrict__ A,
                                                const unsigned short* __restrict__ Bw,
                                                const float* __restrict__ bias,
                                                float* __restrict__ C) {
  __shared__ unsigned short As[64 * 64];    //  8 KB
  __shared__ unsigned short Bs[128 * 64];   // 16 KB
  const int lin = blockIdx.x;               // 0..1023
  const int xcd = lin & 7, loc = lin >> 3;
  const int cb = loc & 1, rp = xcd * 64 + (loc >> 1);
  const int row0 = rp * 64, col0 = cb * 128;
  const unsigned short* Bp = Bw + (size_t)(row0 >> 13) * 65536;   // per-b W3 [256][256]
  const int t = threadIdx.x, l = t & 63, w = t >> 6;
  const int wr = (w >> 1) * 32, wc = (w & 1) * 64;
  f32x4 acc[2][4] = {};
  for (int k0 = 0; k0 < 256; k0 += 64) {
#pragma unroll
    for (int p = 0; p < 2; ++p) {
      const unsigned short* ga = A + (size_t)(row0 + p * 32 + (t >> 3)) * 256 + k0 + ((t & 7) << 3);
      __builtin_amdgcn_global_load_lds(
          (const __attribute__((address_space(1))) void*)ga,
          (__attribute__((address_space(3))) void*)((char*)As + p * 4096 + t * 16), 16, 0, 0);
    }
#pragma unroll
    for (int p = 0; p < 4; ++p) {
      const unsigned short* gb = Bp + (size_t)(col0 + p * 32 + (t >> 3)) * 256 + k0 + ((t & 7) << 3);
      __builtin_amdgcn_global_load_lds(
          (const __attribute__((address_space(1))) void*)gb,
          (__attribute__((address_space(3))) void*)((char*)Bs + p * 4096 + t * 16), 16, 0, 0);
    }
    __syncthreads();
#pragma unroll
    for (int ks = 0; ks < 2; ++ks) {
      bf16x8 af[2], bfr[4];
#pragma unroll
      for (int mt = 0; mt < 2; ++mt)
        af[mt] = *reinterpret_cast<const bf16x8*>(
            &As[(wr + mt * 16 + (l & 15)) * 64 + ks * 32 + (l >> 4) * 8]);
#pragma unroll
      for (int nt = 0; nt < 4; ++nt)
        bfr[nt] = *reinterpret_cast<const bf16x8*>(
            &Bs[(wc + nt * 16 + (l & 15)) * 64 + ks * 32 + (l >> 4) * 8]);
#pragma unroll
      for (int mt = 0; mt < 2; ++mt)
#pragma unroll
        for (int nt = 0; nt < 4; ++nt)
          acc[mt][nt] = __builtin_amdgcn_mfma_f32_16x16x32_bf16(af[mt], bfr[nt], acc[mt][nt], 0, 0, 0);
    }
    __syncthreads();
  }
#pragma unroll
  for (int mt = 0; mt < 2; ++mt)
#pragma unroll
    for (int nt = 0; nt < 4; ++nt) {
      const int col = col0 + wc + nt * 16 + (l & 15);
      const float bv = bias[col];
#pragma unroll
      for (int i = 0; i < 4; ++i) {
        const int row = row0 + wr + mt * 16 + ((l >> 4) << 2) + i;
        C[(size_t)row * 256 + col] = acc[mt][nt][i] + bv;
      }
    }
}

// ---------------------------------------------------------------- launch
extern "C" void kernel_launch(void* const* d_in, const int* in_sizes, int n_in,
                              void* d_out, int out_size, void* d_ws, size_t ws_size,
                              hipStream_t stream) {
  const float* x    = (const float*)d_in[0];   // [4,8192,256]
  const float* Wqkv = (const float*)d_in[1];   // [1536,256]
  const float* Wout = (const float*)d_in[2];   // [256,512]
  const float* bout = (const float*)d_in[3];   // [256]
  char* ws = (char*)d_ws;
  unsigned short* xb    = (unsigned short*)(ws);                 // 16,777,216 B
  unsigned short* wqkvb = (unsigned short*)(ws + 16777216);      //    786,432 B
  unsigned short* wqT   = (unsigned short*)(ws + 17563648);      //    262,144 B  [256,512]
  float*          part  = (float*)         (ws + 17825792);      //  8,388,608 B
  float*          dots  = (float*)         (ws + 26214400);      //    524,288 B
  unsigned short* m2    = (unsigned short*)(ws + 26738688);      //  1,048,576 B  [1024,512]
  unsigned short* w3    = (unsigned short*)(ws + 27787264);      //    524,288 B  [1024,256]

  (void)hipFuncSetAttribute((const void*)kvdots_kernel,
                            hipFuncAttributeMaxDynamicSharedMemorySize, KVD_LDS);

  prep_kernel<<<dim3(8576), 256, 0, stream>>>(x, Wqkv, xb, wqkvb, wqT);
  // fused kv-GEMM + instance-norm + k^T v partials (kvb never materialized)
  kvdots_kernel<<<dim3(512), 512, KVD_LDS, stream>>>(xb, wqkvb, part);
  reduce_kernel<<<dim3(128), 256, 0, stream>>>(part, dots);
  // M2 = (1/n) dots @ Wout  (bf16 [1024,512])
  m2_kernel<<<dim3(4, 256), 512, 0, stream>>>(dots, Wout, m2);
  // W3 = M2 @ Wq^T  (bf16 [1024,256] = per-batch [4][256][256])
  gemm_kernel<512, 512, 256><<<dim3(2, 8), 256, 0, stream>>>(m2, wqT, w3);
  // out = x @ W3^T + bout -> f32 [32768,256]
  gemm_out<<<dim3(1024), 256, 0, stream>>>(xb, w3, bout, (float*)d_out);
}